// Round 3
// baseline (377.049 us; speedup 1.0000x reference)
//
#include <hip/hip_runtime.h>

#define NT 16384
#define NH 2048
#define NE 64
#define TOPK 8
#define TT 32            // tokens per block
#define KQ 128           // float4-quads per wave k-slice (512 floats, k-split 4)

// output layout (floats)
#define LOFF 0
#define WOFF (NT * NE)
#define IOFF (WOFF + NT * TOPK)
#define MOFF (IOFF + NT * TOPK)

__global__ __launch_bounds__(256, 2)
void router_kernel(const float* __restrict__ X, const float* __restrict__ Wg,
                   const float* __restrict__ bg, float* __restrict__ out) {
    __shared__ float P[3 * TT * NE];     // k-split partials from waves 1..3 (24KB)
    __shared__ float Ls[TT][NE + 1];     // logits tile (8.3KB)

    const int tid   = threadIdx.x;
    const int wave  = tid >> 6;          // k-split id 0..3
    const int lane  = tid & 63;
    const int eg    = lane >> 3;         // 0..7
    const int tg    = lane & 7;          // 0..7
    const int e0    = eg * 8;            // 8 experts per thread
    const int t0    = tg * 4;            // 4 tokens per thread
    const int tbase = blockIdx.x * TT;
    const int k0    = wave * (NH / 4);   // 512*wave

    const float4* xp[4];
    const float4* wp[8];
#pragma unroll
    for (int j = 0; j < 4; j++)
        xp[j] = (const float4*)(X + (size_t)(tbase + t0 + j) * NH + k0);
#pragma unroll
    for (int i = 0; i < 8; i++)
        wp[i] = (const float4*)(Wg + (size_t)(e0 + i) * NH + k0);

    float acc[4][8];
#pragma unroll
    for (int j = 0; j < 4; j++)
#pragma unroll
        for (int i = 0; i < 8; i++) acc[j][i] = 0.0f;

    float4 xa[4], wa[8], xb[4], wb[8];
#pragma unroll
    for (int j = 0; j < 4; j++) xa[j] = xp[j][0];
#pragma unroll
    for (int i = 0; i < 8; i++) wa[i] = wp[i][0];

    for (int c = 0; c < KQ; c += 2) {
        // prefetch c+1 while computing c
#pragma unroll
        for (int j = 0; j < 4; j++) xb[j] = xp[j][c + 1];
#pragma unroll
        for (int i = 0; i < 8; i++) wb[i] = wp[i][c + 1];

#pragma unroll
        for (int j = 0; j < 4; j++)
#pragma unroll
            for (int i = 0; i < 8; i++) {
                acc[j][i] = fmaf(xa[j].x, wa[i].x, acc[j][i]);
                acc[j][i] = fmaf(xa[j].y, wa[i].y, acc[j][i]);
                acc[j][i] = fmaf(xa[j].z, wa[i].z, acc[j][i]);
                acc[j][i] = fmaf(xa[j].w, wa[i].w, acc[j][i]);
            }

        if (c + 2 < KQ) {
#pragma unroll
            for (int j = 0; j < 4; j++) xa[j] = xp[j][c + 2];
#pragma unroll
            for (int i = 0; i < 8; i++) wa[i] = wp[i][c + 2];
        }

#pragma unroll
        for (int j = 0; j < 4; j++)
#pragma unroll
            for (int i = 0; i < 8; i++) {
                acc[j][i] = fmaf(xb[j].x, wb[i].x, acc[j][i]);
                acc[j][i] = fmaf(xb[j].y, wb[i].y, acc[j][i]);
                acc[j][i] = fmaf(xb[j].z, wb[i].z, acc[j][i]);
                acc[j][i] = fmaf(xb[j].w, wb[i].w, acc[j][i]);
            }
    }

    // ---- k-split reduction: waves 1..3 dump partials to LDS ----
    if (wave != 0) {
        const int pb = (wave - 1) * (TT * NE);
#pragma unroll
        for (int j = 0; j < 4; j++) {
            *(float4*)&P[pb + (t0 + j) * NE + e0]     =
                make_float4(acc[j][0], acc[j][1], acc[j][2], acc[j][3]);
            *(float4*)&P[pb + (t0 + j) * NE + e0 + 4] =
                make_float4(acc[j][4], acc[j][5], acc[j][6], acc[j][7]);
        }
    }
    __syncthreads();

    if (wave == 0) {
        // reduce partials + bias -> Ls
#pragma unroll
        for (int s = 0; s < 3; s++)
#pragma unroll
            for (int j = 0; j < 4; j++) {
                float4 p0 = *(const float4*)&P[s * (TT * NE) + (t0 + j) * NE + e0];
                float4 p1 = *(const float4*)&P[s * (TT * NE) + (t0 + j) * NE + e0 + 4];
                acc[j][0] += p0.x; acc[j][1] += p0.y; acc[j][2] += p0.z; acc[j][3] += p0.w;
                acc[j][4] += p1.x; acc[j][5] += p1.y; acc[j][6] += p1.z; acc[j][7] += p1.w;
            }
        float4 b0 = *(const float4*)&bg[e0];
        float4 b1 = *(const float4*)&bg[e0 + 4];
        float bias[8] = {b0.x, b0.y, b0.z, b0.w, b1.x, b1.y, b1.z, b1.w};
#pragma unroll
        for (int j = 0; j < 4; j++)
#pragma unroll
            for (int i = 0; i < 8; i++)
                Ls[t0 + j][e0 + i] = acc[j][i] + bias[i];
    } else {
        // waves 1..3: zero this block's mask slab (512 segs x 32 cols)
        float4 z = make_float4(0.f, 0.f, 0.f, 0.f);
        for (int m = tid - 64; m < 4096; m += 192) {
            int seg = m >> 3;            // 0..511
            int off = (m & 7) << 2;      // 0..28
            *(float4*)(out + MOFF + (size_t)seg * NT + tbase + off) = z;
        }
    }
    __syncthreads();

    // ---- coalesced logits write from Ls ----
#pragma unroll
    for (int v = 0; v < 2; v++) {
        int f  = v * 256 + tid;          // 0..511 float4s
        int t  = f >> 4;
        int c4 = (f & 15) << 2;
        float4 o = make_float4(Ls[t][c4], Ls[t][c4 + 1], Ls[t][c4 + 2], Ls[t][c4 + 3]);
        *(float4*)(out + LOFF + (size_t)(tbase + t) * NE + c4) = o;
    }

    // ---- per-token top-8 + weights + indices + mask scatter ----
    if (tid < TT) {
        const int t = tid;
        const size_t gt = (size_t)(tbase + t);

        float m = -1e30f;
#pragma unroll
        for (int e = 0; e < NE; e++) m = fmaxf(m, Ls[t][e]);

        unsigned long long sel = 0ULL;
        int   idxs[TOPK];
        float vals[TOPK];
#pragma unroll
        for (int k = 0; k < TOPK; k++) {
            float best = -1e30f;
            int   bi   = 0;
            for (int e = 0; e < NE; e++) {
                if (!((sel >> e) & 1ULL)) {
                    float v = Ls[t][e];
                    if (v > best) { best = v; bi = e; }  // strict >: lowest index wins ties
                }
            }
            sel |= (1ULL << bi);
            idxs[k] = bi;
            vals[k] = best;
        }

        float ex[TOPK];
        float s = 0.0f;
#pragma unroll
        for (int k = 0; k < TOPK; k++) { ex[k] = __expf(vals[k] - m); s += ex[k]; }
        float inv = 1.0f / s;

#pragma unroll
        for (int k = 0; k < TOPK; k++) {
            out[WOFF + gt * TOPK + k] = ex[k] * inv;
            out[IOFF + gt * TOPK + k] = (float)idxs[k];
            out[MOFF + (size_t)idxs[k] * (TOPK * NT) + (size_t)k * NT + gt] = 1.0f;
        }
    }
}

extern "C" void kernel_launch(void* const* d_in, const int* in_sizes, int n_in,
                              void* d_out, int out_size, void* d_ws, size_t ws_size,
                              hipStream_t stream) {
    const float* X  = (const float*)d_in[0];
    const float* Wg = (const float*)d_in[1];
    const float* bg = (const float*)d_in[2];
    float* out = (float*)d_out;

    hipLaunchKernelGGL(router_kernel, dim3(NT / TT), dim3(256), 0, stream,
                       X, Wg, bg, out);
}

// Round 4
// 286.963 us; speedup vs baseline: 1.3139x; 1.3139x over previous
//
#include <hip/hip_runtime.h>

#define NT 16384
#define NH 2048
#define NE 64
#define TOPK 8
#define TT 64
#define KT 32
#define NTILES (NH / KT)   // 64

// output layout (floats)
#define LOFF 0
#define WOFF (NT * NE)
#define IOFF (WOFF + NT * TOPK)
#define MOFF (IOFF + NT * TOPK)

#define SWZ(r) (((r) + ((r) >> 3)) & 7)

typedef const __attribute__((address_space(1))) unsigned int* gptr_t;
typedef __attribute__((address_space(3))) unsigned int* lptr_t;

__global__ __launch_bounds__(512, 2)
void router_kernel(const float* __restrict__ X, const float* __restrict__ Wg,
                   const float* __restrict__ bg, float* __restrict__ out) {
    // SBUF: X dbuf [2][2048] @0, W dbuf [2][2048] @4096 (32KB); reused as P slots 0,1
    __shared__ float SBUF[8192];
    __shared__ float PEXT[5 * 4096];   // partial slots 2..6 (80KB)
    __shared__ float Ls[TT][NE + 1];   // logits tile, pad 65 (16.6KB)

    const int tid  = threadIdx.x;
    const int wave = tid >> 6;         // 0..7 = my k-quad within each tile
    const int lane = tid & 63;
    const int eg = lane >> 3, tg = lane & 7;
    const int e0 = eg * 8, t0 = tg * 8;
    const int tbase = blockIdx.x * TT;

    // ---- staging: granule g = tid -> (row = tid>>3, stored quad = tid&7) ----
    const int srow = tid >> 3;                 // 0..63
    const int qsrc = (tid & 7) ^ SWZ(srow);    // source quad (swizzle at load)
    const float* xsrc = X  + (size_t)(tbase + srow) * NH + qsrc * 4;
    const float* wsrc = Wg + (size_t)srow * NH + qsrc * 4;
    // wave-uniform LDS bases (HW writes lane i at base + i*16B)
    const int xbase0 = wave * 256;             // + buf*2048
    const int wbase0 = 4096 + wave * 256;      // + buf*2048

    // ---- compute-read offsets (swizzled) ----
    int xoff[8], woff[8];
#pragma unroll
    for (int j = 0; j < 8; j++) xoff[j] = (t0 + j) * 32 + ((wave ^ ((tg + j) & 7)) << 2);
#pragma unroll
    for (int i = 0; i < 8; i++) woff[i] = (e0 + i) * 32 + ((wave ^ ((eg + i) & 7)) << 2);

    float acc[8][8];
#pragma unroll
    for (int j = 0; j < 8; j++)
#pragma unroll
        for (int i = 0; i < 8; i++) acc[j][i] = 0.0f;

    // prefetch tile 0 -> buf 0
    __builtin_amdgcn_global_load_lds((gptr_t)xsrc, (lptr_t)&SBUF[xbase0], 16, 0, 0);
    __builtin_amdgcn_global_load_lds((gptr_t)wsrc, (lptr_t)&SBUF[wbase0], 16, 0, 0);

    int buf = 0;
    for (int kt = 0; kt < NTILES; kt++) {
        __syncthreads();   // tile kt resident in buf
        if (kt + 1 < NTILES) {
            const int nb = (buf ^ 1) * 2048;
            const int go = (kt + 1) * KT;
            __builtin_amdgcn_global_load_lds((gptr_t)(xsrc + go), (lptr_t)&SBUF[xbase0 + nb], 16, 0, 0);
            __builtin_amdgcn_global_load_lds((gptr_t)(wsrc + go), (lptr_t)&SBUF[wbase0 + nb], 16, 0, 0);
        }
        const float* xb = &SBUF[buf * 2048];
        const float* wb = &SBUF[4096 + buf * 2048];
        float4 xr[8], wr[8];
#pragma unroll
        for (int j = 0; j < 8; j++) xr[j] = *(const float4*)&xb[xoff[j]];
#pragma unroll
        for (int i = 0; i < 8; i++) wr[i] = *(const float4*)&wb[woff[i]];
#pragma unroll
        for (int j = 0; j < 8; j++)
#pragma unroll
            for (int i = 0; i < 8; i++) {
                acc[j][i] = fmaf(xr[j].x, wr[i].x, acc[j][i]);
                acc[j][i] = fmaf(xr[j].y, wr[i].y, acc[j][i]);
                acc[j][i] = fmaf(xr[j].z, wr[i].z, acc[j][i]);
                acc[j][i] = fmaf(xr[j].w, wr[i].w, acc[j][i]);
            }
        buf ^= 1;
    }
    __syncthreads();   // all ds_reads of last tile done; stage area reusable

    // ---- k-split reduction: waves 1..7 dump partials (slot w-1) ----
    if (wave != 0) {
        float* ps = (wave <= 2) ? &SBUF[(wave - 1) * 4096] : &PEXT[(wave - 3) * 4096];
#pragma unroll
        for (int j = 0; j < 8; j++) {
            *(float4*)&ps[(t0 + j) * 64 + e0] =
                make_float4(acc[j][0], acc[j][1], acc[j][2], acc[j][3]);
            *(float4*)&ps[(t0 + j) * 64 + e0 + 4] =
                make_float4(acc[j][4], acc[j][5], acc[j][6], acc[j][7]);
        }
    }
    __syncthreads();

    if (wave == 0) {
        // sum 7 partials + bias -> Ls
#pragma unroll
        for (int s = 0; s < 7; s++) {
            const float* ps = (s < 2) ? &SBUF[s * 4096] : &PEXT[(s - 2) * 4096];
#pragma unroll
            for (int j = 0; j < 8; j++) {
                float4 p0 = *(const float4*)&ps[(t0 + j) * 64 + e0];
                float4 p1 = *(const float4*)&ps[(t0 + j) * 64 + e0 + 4];
                acc[j][0] += p0.x; acc[j][1] += p0.y; acc[j][2] += p0.z; acc[j][3] += p0.w;
                acc[j][4] += p1.x; acc[j][5] += p1.y; acc[j][6] += p1.z; acc[j][7] += p1.w;
            }
        }
        float4 b0 = *(const float4*)&bg[e0];
        float4 b1 = *(const float4*)&bg[e0 + 4];
        float bias[8] = {b0.x, b0.y, b0.z, b0.w, b1.x, b1.y, b1.z, b1.w};
#pragma unroll
        for (int j = 0; j < 8; j++)
#pragma unroll
            for (int i = 0; i < 8; i++)
                Ls[t0 + j][e0 + i] = acc[j][i] + bias[i];
    } else {
        // waves 1..7 (448 threads): zero this block's mask slab (512 segs x 64 tokens)
        float4 z = make_float4(0.f, 0.f, 0.f, 0.f);
        for (int m = tid - 64; m < 8192; m += 448) {
            int seg = m >> 4;            // 0..511
            int off = (m & 15) << 2;     // 0..60
            *(float4*)(out + MOFF + (size_t)seg * NT + tbase + off) = z;
        }
    }
    __syncthreads();

    // ---- coalesced logits write from Ls (all 512 threads) ----
#pragma unroll
    for (int v = 0; v < 2; v++) {
        int f  = v * 512 + tid;          // 0..1023 float4s
        int t  = f >> 4;
        int c4 = (f & 15) << 2;
        float4 o = make_float4(Ls[t][c4], Ls[t][c4 + 1], Ls[t][c4 + 2], Ls[t][c4 + 3]);
        *(float4*)(out + LOFF + (size_t)(tbase + t) * NE + c4) = o;
    }

    // ---- per-token top-8 + weights + indices + mask scatter ----
    if (tid < TT) {
        const int t = tid;
        const size_t gt = (size_t)(tbase + t);

        float m = -1e30f;
#pragma unroll
        for (int e = 0; e < NE; e++) m = fmaxf(m, Ls[t][e]);

        unsigned long long sel = 0ULL;
        int   idxs[TOPK];
        float vals[TOPK];
#pragma unroll
        for (int k = 0; k < TOPK; k++) {
            float best = -1e30f;
            int   bi   = 0;
            for (int e = 0; e < NE; e++) {
                if (!((sel >> e) & 1ULL)) {
                    float v = Ls[t][e];
                    if (v > best) { best = v; bi = e; }  // strict >: lowest index wins ties
                }
            }
            sel |= (1ULL << bi);
            idxs[k] = bi;
            vals[k] = best;
        }

        float ex[TOPK];
        float s = 0.0f;
#pragma unroll
        for (int k = 0; k < TOPK; k++) { ex[k] = __expf(vals[k] - m); s += ex[k]; }
        float inv = 1.0f / s;

#pragma unroll
        for (int k = 0; k < TOPK; k++) {
            out[WOFF + gt * TOPK + k] = ex[k] * inv;
            out[IOFF + gt * TOPK + k] = (float)idxs[k];
            out[MOFF + (size_t)idxs[k] * (TOPK * NT) + (size_t)k * NT + gt] = 1.0f;
        }
    }
}

extern "C" void kernel_launch(void* const* d_in, const int* in_sizes, int n_in,
                              void* d_out, int out_size, void* d_ws, size_t ws_size,
                              hipStream_t stream) {
    const float* X  = (const float*)d_in[0];
    const float* Wg = (const float*)d_in[1];
    const float* bg = (const float*)d_in[2];
    float* out = (float*)d_out;

    hipLaunchKernelGGL(router_kernel, dim3(NT / TT), dim3(512), 0, stream,
                       X, Wg, bg, out);
}

// Round 5
// 240.435 us; speedup vs baseline: 1.5682x; 1.1935x over previous
//
#include <hip/hip_runtime.h>

#define NT 16384
#define NH 2048
#define NE 64
#define TOPK 8
#define TT 64
#define KC 64
#define NCH (NH / KC)   // 32 chunks

// output layout (floats)
#define LOFF 0
#define WOFF (NT * NE)
#define IOFF (WOFF + NT * TOPK)
#define MOFF (IOFF + NT * TOPK)

typedef __attribute__((ext_vector_type(8))) short short8;
typedef __attribute__((ext_vector_type(4))) float floatx4;

union FragU { uint4 u; short8 s; };

// exact triple split of (a,b) into 3 packed bf16 words (truncation; residual 2^-24)
__device__ __forceinline__ unsigned pack3(float a, float b, unsigned& w1, unsigned& w2) {
    unsigned au = __float_as_uint(a), bu = __float_as_uint(b);
    unsigned ah0 = au & 0xFFFF0000u, bh0 = bu & 0xFFFF0000u;
    float ra = a - __uint_as_float(ah0);
    float rb = b - __uint_as_float(bh0);
    unsigned ar = __float_as_uint(ra), br = __float_as_uint(rb);
    unsigned ah1 = ar & 0xFFFF0000u, bh1 = br & 0xFFFF0000u;
    float sa = ra - __uint_as_float(ah1);
    float sb = rb - __uint_as_float(bh1);
    w1 = bh1 | (ah1 >> 16);
    w2 = (__float_as_uint(sb) & 0xFFFF0000u) | (__float_as_uint(sa) >> 16);
    return bh0 | (ah0 >> 16);
}

__global__ __launch_bounds__(512, 1)
void router_kernel(const float* __restrict__ X, const float* __restrict__ Wg,
                   const float* __restrict__ bg, float* __restrict__ out) {
    // planes: [buf][0..2 = X0..X2, 3..5 = W0..W2][row][64 bf16] = 96KB
    __shared__ unsigned short SP[2][6][64][64];
    __shared__ float P[64 * 64];       // k-split partials (16KB)
    __shared__ float Ls[TT][NE + 1];   // logits tile (16.6KB)

    const int tid  = threadIdx.x;
    const int wave = tid >> 6;
    const int l    = tid & 63;
    const int tp = wave & 1, ep = (wave >> 1) & 1, kh = wave >> 2;  // tile-pair / k-half
    const int tbase = blockIdx.x * TT;

    // ---- staging geometry: thread -> (row, 8-float group) ----
    const int srow = tid >> 3;                // 0..63
    const int g8   = tid & 7;                 // 0..7
    const int spg  = g8 ^ (srow & 7);         // swizzled store granule
    const float* xrow = X  + (size_t)(tbase + srow) * NH + g8 * 8;
    const float* wrow = Wg + (size_t)srow * NH + g8 * 8;

    // ---- compute geometry ----
    const int lr = l & 15, lq = l >> 4;

    floatx4 acc[2][2];
#pragma unroll
    for (int a = 0; a < 2; a++)
#pragma unroll
        for (int b = 0; b < 2; b++) acc[a][b] = (floatx4)0.0f;

    // preload chunk 0
    float4 xl0 = *(const float4*)(xrow);
    float4 xl1 = *(const float4*)(xrow + 4);
    float4 wl0 = *(const float4*)(wrow);
    float4 wl1 = *(const float4*)(wrow + 4);

    for (int k = 0; k < NCH; k++) {
        const int bsel = k & 1;
        // ---- convert + stage chunk k ----
        unsigned xw1[4], xw2[4], ww1[4], ww2[4];
        uint4 x0, w0, x1, x2, w1v, w2v;
        x0.x = pack3(xl0.x, xl0.y, xw1[0], xw2[0]);
        x0.y = pack3(xl0.z, xl0.w, xw1[1], xw2[1]);
        x0.z = pack3(xl1.x, xl1.y, xw1[2], xw2[2]);
        x0.w = pack3(xl1.z, xl1.w, xw1[3], xw2[3]);
        w0.x = pack3(wl0.x, wl0.y, ww1[0], ww2[0]);
        w0.y = pack3(wl0.z, wl0.w, ww1[1], ww2[1]);
        w0.z = pack3(wl1.x, wl1.y, ww1[2], ww2[2]);
        w0.w = pack3(wl1.z, wl1.w, ww1[3], ww2[3]);
        x1 = make_uint4(xw1[0], xw1[1], xw1[2], xw1[3]);
        x2 = make_uint4(xw2[0], xw2[1], xw2[2], xw2[3]);
        w1v = make_uint4(ww1[0], ww1[1], ww1[2], ww1[3]);
        w2v = make_uint4(ww2[0], ww2[1], ww2[2], ww2[3]);
        *(uint4*)&SP[bsel][0][srow][spg * 8] = x0;
        *(uint4*)&SP[bsel][1][srow][spg * 8] = x1;
        *(uint4*)&SP[bsel][2][srow][spg * 8] = x2;
        *(uint4*)&SP[bsel][3][srow][spg * 8] = w0;
        *(uint4*)&SP[bsel][4][srow][spg * 8] = w1v;
        *(uint4*)&SP[bsel][5][srow][spg * 8] = w2v;
        __syncthreads();

        // prefetch chunk k+1 into registers (overlaps compute)
        if (k + 1 < NCH) {
            const int go = (k + 1) * KC;
            xl0 = *(const float4*)(xrow + go);
            xl1 = *(const float4*)(xrow + go + 4);
            wl0 = *(const float4*)(wrow + go);
            wl1 = *(const float4*)(wrow + go + 4);
        }

        // ---- MFMA on my k-half ----
        if ((k >> 4) == kh) {
#pragma unroll
            for (int s = 0; s < 2; s++) {
                short8 af[2][3], bf[2][3];
#pragma unroll
                for (int a = 0; a < 2; a++) {
                    const int row = (tp * 2 + a) * 16 + lr;
                    const int pgr = (s * 4 + lq) ^ (lr & 7);
#pragma unroll
                    for (int p = 0; p < 3; p++) {
                        FragU t; t.u = *(const uint4*)&SP[bsel][p][row][pgr * 8];
                        af[a][p] = t.s;
                    }
                }
#pragma unroll
                for (int b = 0; b < 2; b++) {
                    const int row = (ep * 2 + b) * 16 + lr;
                    const int pgr = (s * 4 + lq) ^ (lr & 7);
#pragma unroll
                    for (int p = 0; p < 3; p++) {
                        FragU t; t.u = *(const uint4*)&SP[bsel][3 + p][row][pgr * 8];
                        bf[b][p] = t.s;
                    }
                }
#pragma unroll
                for (int a = 0; a < 2; a++)
#pragma unroll
                    for (int b = 0; b < 2; b++) {
                        acc[a][b] = __builtin_amdgcn_mfma_f32_16x16x32_bf16(af[a][0], bf[b][0], acc[a][b], 0, 0, 0);
                        acc[a][b] = __builtin_amdgcn_mfma_f32_16x16x32_bf16(af[a][0], bf[b][1], acc[a][b], 0, 0, 0);
                        acc[a][b] = __builtin_amdgcn_mfma_f32_16x16x32_bf16(af[a][1], bf[b][0], acc[a][b], 0, 0, 0);
                        acc[a][b] = __builtin_amdgcn_mfma_f32_16x16x32_bf16(af[a][1], bf[b][1], acc[a][b], 0, 0, 0);
                        acc[a][b] = __builtin_amdgcn_mfma_f32_16x16x32_bf16(af[a][0], bf[b][2], acc[a][b], 0, 0, 0);
                        acc[a][b] = __builtin_amdgcn_mfma_f32_16x16x32_bf16(af[a][2], bf[b][0], acc[a][b], 0, 0, 0);
                    }
            }
        }
    }
    __syncthreads();

    // ---- k-split reduction: kh=1 waves dump partials ----
    if (kh == 1) {
#pragma unroll
        for (int a = 0; a < 2; a++)
#pragma unroll
            for (int b = 0; b < 2; b++)
#pragma unroll
                for (int r = 0; r < 4; r++) {
                    const int tok = (tp * 2 + a) * 16 + lq * 4 + r;
                    const int exp = (ep * 2 + b) * 16 + lr;
                    P[tok * 64 + exp] = acc[a][b][r];
                }
    }
    __syncthreads();

    if (kh == 0) {
        // reduce + bias -> Ls
#pragma unroll
        for (int b = 0; b < 2; b++) {
            const int exp = (ep * 2 + b) * 16 + lr;
            const float bias = bg[exp];
#pragma unroll
            for (int a = 0; a < 2; a++)
#pragma unroll
                for (int r = 0; r < 4; r++) {
                    const int tok = (tp * 2 + a) * 16 + lq * 4 + r;
                    Ls[tok][exp] = acc[a][b][r] + P[tok * 64 + exp] + bias;
                }
        }
    } else {
        // kh=1 waves (tid 256..511): zero this block's mask slab
        float4 z = make_float4(0.f, 0.f, 0.f, 0.f);
        for (int m = tid - 256; m < 8192; m += 256) {
            int seg = m >> 4;            // 0..511
            int off = (m & 15) << 2;     // 0..60
            *(float4*)(out + MOFF + (size_t)seg * NT + tbase + off) = z;
        }
    }
    __syncthreads();

    // ---- coalesced logits write ----
#pragma unroll
    for (int v = 0; v < 2; v++) {
        int f  = v * 512 + tid;          // 0..1023 float4s
        int t  = f >> 4;
        int c4 = (f & 15) << 2;
        float4 o = make_float4(Ls[t][c4], Ls[t][c4 + 1], Ls[t][c4 + 2], Ls[t][c4 + 3]);
        *(float4*)(out + LOFF + (size_t)(tbase + t) * NE + c4) = o;
    }

    // ---- per-token top-8 + weights + indices + mask scatter ----
    if (tid < TT) {
        const int t = tid;
        const size_t gt = (size_t)(tbase + t);

        float m = -1e30f;
#pragma unroll
        for (int e = 0; e < NE; e++) m = fmaxf(m, Ls[t][e]);

        unsigned long long sel = 0ULL;
        int   idxs[TOPK];
        float vals[TOPK];
#pragma unroll
        for (int kk = 0; kk < TOPK; kk++) {
            float best = -1e30f;
            int   bi   = 0;
            for (int e = 0; e < NE; e++) {
                if (!((sel >> e) & 1ULL)) {
                    float v = Ls[t][e];
                    if (v > best) { best = v; bi = e; }  // strict >: lowest index wins ties
                }
            }
            sel |= (1ULL << bi);
            idxs[kk] = bi;
            vals[kk] = best;
        }

        float ex[TOPK];
        float s = 0.0f;
#pragma unroll
        for (int kk = 0; kk < TOPK; kk++) { ex[kk] = __expf(vals[kk] - m); s += ex[kk]; }
        float inv = 1.0f / s;

#pragma unroll
        for (int kk = 0; kk < TOPK; kk++) {
            out[WOFF + gt * TOPK + kk] = ex[kk] * inv;
            out[IOFF + gt * TOPK + kk] = (float)idxs[kk];
            out[MOFF + (size_t)idxs[kk] * (TOPK * NT) + (size_t)kk * NT + gt] = 1.0f;
        }
    }
}

extern "C" void kernel_launch(void* const* d_in, const int* in_sizes, int n_in,
                              void* d_out, int out_size, void* d_ws, size_t ws_size,
                              hipStream_t stream) {
    const float* X  = (const float*)d_in[0];
    const float* Wg = (const float*)d_in[1];
    const float* bg = (const float*)d_in[2];
    float* out = (float*)d_out;

    hipLaunchKernelGGL(router_kernel, dim3(NT / TT), dim3(512), 0, stream,
                       X, Wg, bg, out);
}